// Round 20
// baseline (112.881 us; speedup 1.0000x reference)
//
#include <hip/hip_runtime.h>

#define B_    1024
#define AB_   6
#define BIN_  16
#define BOUT_ 32

typedef float f4 __attribute__((ext_vector_type(4)));
typedef _Float16 hlf4 __attribute__((ext_vector_type(4)));

// out[slice, o, l, k] = sum_i X[slice, i, l] * W[ab, i, o, k]
//
// R20 = R19 + LDS PING-PONG (one barrier per unit; flush of unit u-1
// overlaps compute of unit u in the same barrier window).
// Unit = half-slice (o 0..15 / 16..31) for l8/l6 (2 bufs x 18.5 KB fit the
// same 37 KB), full slice for l4/l2. Per iteration:
//   barrier -> flush(prev, buf[(u-1)&1]) -> A-prefetch -> compute(buf[u&1])
// Safety: compute(u) overwrites buf last READ by flush(u-2), whose ds_reads
// completed before those waves hit the previous barrier (store data regs
// consumed); flush(u-1) reads writes made visible by this barrier. 
// B-frags per half are literal-indexed (no runtime-indexed reg arrays).
template<int NSH, int NHALF, int SPB>
__device__ __forceinline__ void pipe_body(const float* __restrict__ X,
                                          const float* __restrict__ W,
                                          float* __restrict__ OUT,
                                          float* os0, float* os1, int bi) {
    constexpr int SZ    = BIN_ * NSH;
    constexpr int NOUT  = BOUT_ * NSH * NSH;
    constexpr int OPB   = BOUT_ / NHALF;        // o-range per unit
    constexpr int USZ   = OPB * NSH * NSH;      // floats per unit (<= 4624)
    constexpr int NTU   = (OPB * NSH) / 16;     // N-tiles per unit
    constexpr int NTQ   = (NTU + 3) / 4;        // tiles per wave
    constexpr int MT    = (NSH + 15) / 16;      // M-tiles (tail masked)
    constexpr int UNITS = SPB * NHALF;

    const int tid  = threadIdx.x;
    const int lane = tid & 63;
    const int w    = tid >> 6;                  // wave 0..3
    const int lm   = lane & 15;                 // A-row / B-col / D-col
    const int lk   = (lane >> 4) * 4;           // k-chunk / D row-chunk

    const int ab = bi % AB_;
    const int g  = bi / AB_;
    const int s0 = g * SPB;                     // first slice-index t

    const float* Wab = W + (size_t)ab * (BIN_ * BOUT_ * NSH);

    // ---- hoist B-frags for all halves (literal h,t indices only) ----
    hlf4 bfrag[NHALF][NTQ];
#pragma unroll
    for (int h = 0; h < NHALF; ++h)
#pragma unroll
        for (int t = 0; t < NTQ; ++t) {
            const int ni = w * NTQ + t;
            if (ni < NTU) {
                const int n = h * (OPB * NSH) + ni * 16 + lm;
#pragma unroll
                for (int j = 0; j < 4; ++j)
                    bfrag[h][t][j] = (_Float16)Wab[(lk + j) * (BOUT_ * NSH) + n];
            }
        }

    hlf4 acur[MT], anext[MT];

    auto load_a = [&](int t, hlf4* dst) {       // A[row=l][k] = X[k][l]
        const float* Xs = X + (size_t)(ab + AB_ * t) * SZ;
#pragma unroll
        for (int mi = 0; mi < MT; ++mi) {
            const int l  = mi * 16 + lm;
            const int lc = (l > NSH - 1) ? (NSH - 1) : l;   // clamp, masked later
#pragma unroll
            for (int j = 0; j < 4; ++j)
                dst[mi][j] = (_Float16)Xs[(lk + j) * NSH + lc];
        }
    };

    auto compute = [&](int hh, float* buf) {    // call with LITERAL hh only
#pragma unroll
        for (int t = 0; t < NTQ; ++t) {
            const int ni = w * NTQ + t;
            if (ni < NTU) {
                const int nl = ni * 16 + lm;
                const int ol = nl / NSH;        // constexpr divisor
                const int kq = nl - ol * NSH;
                float* base = buf + ol * (NSH * NSH) + kq;
#pragma unroll
                for (int mi = 0; mi < MT; ++mi) {
                    f4 d = __builtin_amdgcn_mfma_f32_16x16x16f16(
                        acur[mi], bfrag[hh][t], (f4){0.f, 0.f, 0.f, 0.f}, 0, 0, 0);
#pragma unroll
                    for (int j = 0; j < 4; ++j) {
                        const int l = mi * 16 + lk + j;     // D row
                        if (l < NSH) base[l * NSH] = d[j];
                    }
                }
            }
        }
    };

    auto flush = [&](int t, int hh, const float* buf) {     // dense f4 stream
        f4* dst = (f4*)(OUT + (size_t)(ab + AB_ * t) * NOUT + (size_t)hh * USZ);
        const f4* src = (const f4*)buf;
        for (int c = tid; c < USZ / 4; c += 256) dst[c] = src[c];
    };

    // ---- prologue: A(s0), prefetch A(s0+1), compute unit 0 ----
    load_a(s0, acur);
    if (SPB > 1) load_a(s0 + 1, anext);
    compute(0, os0);

    // ---- pipeline: one barrier per unit ----
    for (int u = 1; u < UNITS; ++u) {
        __syncthreads();
        const int s  = u / NHALF;               // NHALF in {1,2} -> shift
        const int h  = u % NHALF;
        const int ps = (u - 1) / NHALF;
        const int ph = (u - 1) % NHALF;

        if (h == 0) {                           // entering new slice
#pragma unroll
            for (int mi = 0; mi < MT; ++mi) acur[mi] = anext[mi];
        }

        flush(s0 + ps, ph, (u & 1) ? os0 : os1);            // issue stores first

        if (h == 0 && s + 1 < SPB) load_a(s0 + s + 1, anext);   // prefetch

        if (NHALF == 2 && h == 1) compute(1, (u & 1) ? os1 : os0);
        else                      compute(0, (u & 1) ? os1 : os0);
    }
    __syncthreads();
    flush(s0 + SPB - 1, NHALF - 1, ((UNITS - 1) & 1) ? os1 : os0);
}

// l=0: direct coalesced stores, 64 n per block.
__device__ __forceinline__ void l0_body(const float* __restrict__ X,
                                        const float* __restrict__ W,
                                        const float* __restrict__ bias,
                                        float* __restrict__ OUT, int b) {
    const int o  = threadIdx.x & 31;
    const int ns = threadIdx.x >> 5;   // 0..7
    const int n0 = (b / AB_) * 64;
    const int ab = b % AB_;
    float wv[BIN_];
#pragma unroll
    for (int i = 0; i < BIN_; ++i) wv[i] = W[(ab * BIN_ + i) * BOUT_ + o];
    const float bv = bias[ab * BOUT_ + o];
#pragma unroll
    for (int s = 0; s < 8; ++s) {
        const int n = n0 + ns + s * 8;
        const float* Xp = X + ((size_t)n * AB_ + ab) * BIN_;
        float acc = bv;
#pragma unroll
        for (int i = 0; i < BIN_; ++i) acc = fmaf(Xp[i], wv[i], acc);
        OUT[((size_t)n * AB_ + ab) * BOUT_ + o] = acc;
    }
}

#define NB8 768   // 6144 slices / SPB 8
#define NB6 768
#define NB4 768
#define NB2 768
#define NB0 96
#define UMAX (16 * 17 * 17)   // unit buffer stride (l8 half-tile, 18.5 KB)

__global__ __launch_bounds__(256, 4)
void s2conv_one(const float* __restrict__ x0, const float* __restrict__ x2,
                const float* __restrict__ x4, const float* __restrict__ x6,
                const float* __restrict__ x8,
                const float* __restrict__ w0, const float* __restrict__ w2,
                const float* __restrict__ w4, const float* __restrict__ w6,
                const float* __restrict__ w8,
                const float* __restrict__ bias, float* __restrict__ out,
                size_t off0, size_t off2, size_t off4, size_t off6, size_t off8) {
    __shared__ __attribute__((aligned(16))) float os[2 * UMAX];   // 37 KB
    int b = blockIdx.x;                        // big degrees first
    if (b < NB8) { pipe_body<17, 2, 8>(x8, w8, out + off8, os, os + UMAX, b); return; }
    b -= NB8;
    if (b < NB6) { pipe_body<13, 2, 8>(x6, w6, out + off6, os, os + UMAX, b); return; }
    b -= NB6;
    if (b < NB4) { pipe_body< 9, 1, 8>(x4, w4, out + off4, os, os + UMAX, b); return; }
    b -= NB4;
    if (b < NB2) { pipe_body< 5, 1, 8>(x2, w2, out + off2, os, os + UMAX, b); return; }
    b -= NB2;
    l0_body(x0, w0, bias, out + off0, b);
}

extern "C" void kernel_launch(void* const* d_in, const int* in_sizes, int n_in,
                              void* d_out, int out_size, void* d_ws, size_t ws_size,
                              hipStream_t stream) {
    const float* x0 = (const float*)d_in[0];
    const float* w0 = (const float*)d_in[1];
    const float* x2 = (const float*)d_in[2];
    const float* w2 = (const float*)d_in[3];
    const float* x4 = (const float*)d_in[4];
    const float* w4 = (const float*)d_in[5];
    const float* x6 = (const float*)d_in[6];
    const float* w6 = (const float*)d_in[7];
    const float* x8 = (const float*)d_in[8];
    const float* w8 = (const float*)d_in[9];
    const float* bias = (const float*)d_in[10];
    float* out = (float*)d_out;

    const size_t per = (size_t)B_ * AB_ * BOUT_;
    size_t off0 = 0;
    size_t off2 = off0 + per * 1;
    size_t off4 = off2 + per * 25;
    size_t off6 = off4 + per * 81;
    size_t off8 = off6 + per * 169;

    const int nblocks = NB8 + NB6 + NB4 + NB2 + NB0;   // 3168
    s2conv_one<<<nblocks, 256, 0, stream>>>(x0, x2, x4, x6, x8,
                                            w0, w2, w4, w6, w8,
                                            bias, out,
                                            off0, off2, off4, off6, off8);
}

// Round 21
// 108.504 us; speedup vs baseline: 1.0403x; 1.0403x over previous
//
#include <hip/hip_runtime.h>

#define B_    1024
#define AB_   6
#define BIN_  16
#define BOUT_ 32

typedef float f4 __attribute__((ext_vector_type(4)));
typedef _Float16 hlf4 __attribute__((ext_vector_type(4)));

// Soft barrier: order LDS only (lgkmcnt), leave global STORES in flight.
// __syncthreads() would emit s_waitcnt vmcnt(0) -> every slice's 36 stores
// drain synchronously through the backed-up HBM queue before any wave
// proceeds (the guide's barrier-drain stall). Stores need no ordering here
// (disjoint addresses across slices); only LDS reuse needs the barrier.
#define SOFTBAR()                                                  \
    do {                                                           \
        asm volatile("s_waitcnt lgkmcnt(0)" ::: "memory");         \
        __builtin_amdgcn_s_barrier();                              \
        __builtin_amdgcn_sched_barrier(0);                         \
    } while (0)

// out[slice, o, l, k] = sum_i X[slice, i, l] * W[ab, i, o, k]
//
// R21 = R19 (fused + MFMA + dense LDS flush + A-prefetch; 108.3us) with the
// two per-slice __syncthreads() replaced by SOFTBAR. Theory: the residual
// ~43us over the 65us store floor is the per-slice vmcnt(0) store drain at
// each barrier (R20's ping-pong kept the same drain -> no win). With
// lgkmcnt-only barriers the store stream pipelines across slices and the
// HBM drain overlaps DS+MFMA continuously.
template<int NSH, int SPB>
__device__ __forceinline__ void mfma_lds_body(const float* __restrict__ X,
                                              const float* __restrict__ W,
                                              float* __restrict__ OUT,
                                              float* os, int bi) {
    constexpr int SZ   = BIN_ * NSH;
    constexpr int NOUT = BOUT_ * NSH * NSH;
    constexpr int NT   = (BOUT_ * NSH) / 16;   // N-tiles
    constexpr int MT   = (NSH + 15) / 16;      // M-tiles (tail rows masked)
    constexpr int NTQ  = (NT + 3) / 4;         // N-tiles per wave

    const int tid  = threadIdx.x;
    const int lane = tid & 63;
    const int w    = tid >> 6;                 // wave 0..3
    const int lm   = lane & 15;                // A-row / B-col / D-col
    const int lk   = (lane >> 4) * 4;          // A/B k-chunk; D row-chunk

    const int ab = bi % AB_;
    const int g  = bi / AB_;

    const float* Wab = W + (size_t)ab * (BIN_ * BOUT_ * NSH);

    // ---- hoist this wave's B-frags once per block ----
    hlf4 bfrag[NTQ];
#pragma unroll
    for (int t = 0; t < NTQ; ++t) {
        const int ni = w * NTQ + t;
        if (ni < NT) {
            const int n = ni * 16 + lm;
#pragma unroll
            for (int j = 0; j < 4; ++j)
                bfrag[t][j] = (_Float16)Wab[(lk + j) * (BOUT_ * NSH) + n];
        }
    }

    auto load_a = [&](int slice, hlf4* dst) {  // A[row=l][k=lk+j] = X[k][l]
        const float* Xs = X + (size_t)slice * SZ;
#pragma unroll
        for (int mi = 0; mi < MT; ++mi) {
            const int l  = mi * 16 + lm;
            const int lc = (l > NSH - 1) ? (NSH - 1) : l;   // clamp, masked later
#pragma unroll
            for (int j = 0; j < 4; ++j)
                dst[mi][j] = (_Float16)Xs[(lk + j) * NSH + lc];
        }
    };

    hlf4 acur[MT], anext[MT];
    load_a(ab + AB_ * (g * SPB), acur);        // prologue

    for (int s = 0; s < SPB; ++s) {
        const int slice = ab + AB_ * (g * SPB + s);

        // ---- this wave's tiles -> LDS ----
#pragma unroll
        for (int t = 0; t < NTQ; ++t) {
            const int ni = w * NTQ + t;
            if (ni < NT) {
                const int n  = ni * 16 + lm;
                const int o  = n / NSH;          // constexpr divisor -> magic mul
                const int kq = n - o * NSH;
                float* base = os + o * (NSH * NSH) + kq;
#pragma unroll
                for (int mi = 0; mi < MT; ++mi) {
                    f4 d = __builtin_amdgcn_mfma_f32_16x16x16f16(
                        acur[mi], bfrag[t], (f4){0.f, 0.f, 0.f, 0.f}, 0, 0, 0);
#pragma unroll
                    for (int j = 0; j < 4; ++j) {
                        const int l = mi * 16 + lk + j;   // D row
                        if (l < NSH) base[l * NSH] = d[j];
                    }
                }
            }
        }
        SOFTBAR();   // ds_writes visible; stores from previous flush stay in flight

        // ---- prefetch next slice's A-frags (latency hides under flush) ----
        if (s + 1 < SPB) load_a(slice + AB_, anext);

        // ---- dense contiguous f4 flush (full 128B lines out) ----
        f4* dst = (f4*)(OUT + (size_t)slice * NOUT);
        const f4* src = (const f4*)os;
        for (int c = tid; c < NOUT / 4; c += 256) dst[c] = src[c];
        SOFTBAR();   // flush ds_reads done -> buffer reusable; stores NOT drained

#pragma unroll
        for (int mi = 0; mi < MT; ++mi) acur[mi] = anext[mi];
    }
}

// l=0: direct coalesced stores, 64 n per block.
__device__ __forceinline__ void l0_body(const float* __restrict__ X,
                                        const float* __restrict__ W,
                                        const float* __restrict__ bias,
                                        float* __restrict__ OUT, int b) {
    const int o  = threadIdx.x & 31;
    const int ns = threadIdx.x >> 5;   // 0..7
    const int n0 = (b / AB_) * 64;
    const int ab = b % AB_;
    float wv[BIN_];
#pragma unroll
    for (int i = 0; i < BIN_; ++i) wv[i] = W[(ab * BIN_ + i) * BOUT_ + o];
    const float bv = bias[ab * BOUT_ + o];
#pragma unroll
    for (int s = 0; s < 8; ++s) {
        const int n = n0 + ns + s * 8;
        const float* Xp = X + ((size_t)n * AB_ + ab) * BIN_;
        float acc = bv;
#pragma unroll
        for (int i = 0; i < BIN_; ++i) acc = fmaf(Xp[i], wv[i], acc);
        OUT[((size_t)n * AB_ + ab) * BOUT_ + o] = acc;
    }
}

#define NB8 768   // 6144 slices / SPB 8
#define NB6 768
#define NB4 768
#define NB2 768
#define NB0 96

__global__ __launch_bounds__(256, 4)
void s2conv_one(const float* __restrict__ x0, const float* __restrict__ x2,
                const float* __restrict__ x4, const float* __restrict__ x6,
                const float* __restrict__ x8,
                const float* __restrict__ w0, const float* __restrict__ w2,
                const float* __restrict__ w4, const float* __restrict__ w6,
                const float* __restrict__ w8,
                const float* __restrict__ bias, float* __restrict__ out,
                size_t off0, size_t off2, size_t off4, size_t off6, size_t off8) {
    __shared__ __attribute__((aligned(16))) float os[BOUT_ * 17 * 17];  // 37 KB
    int b = blockIdx.x;                        // big degrees first
    if (b < NB8) { mfma_lds_body<17, 8>(x8, w8, out + off8, os, b); return; }
    b -= NB8;
    if (b < NB6) { mfma_lds_body<13, 8>(x6, w6, out + off6, os, b); return; }
    b -= NB6;
    if (b < NB4) { mfma_lds_body< 9, 8>(x4, w4, out + off4, os, b); return; }
    b -= NB4;
    if (b < NB2) { mfma_lds_body< 5, 8>(x2, w2, out + off2, os, b); return; }
    b -= NB2;
    l0_body(x0, w0, bias, out + off0, b);
}

extern "C" void kernel_launch(void* const* d_in, const int* in_sizes, int n_in,
                              void* d_out, int out_size, void* d_ws, size_t ws_size,
                              hipStream_t stream) {
    const float* x0 = (const float*)d_in[0];
    const float* w0 = (const float*)d_in[1];
    const float* x2 = (const float*)d_in[2];
    const float* w2 = (const float*)d_in[3];
    const float* x4 = (const float*)d_in[4];
    const float* w4 = (const float*)d_in[5];
    const float* x6 = (const float*)d_in[6];
    const float* w6 = (const float*)d_in[7];
    const float* x8 = (const float*)d_in[8];
    const float* w8 = (const float*)d_in[9];
    const float* bias = (const float*)d_in[10];
    float* out = (float*)d_out;

    const size_t per = (size_t)B_ * AB_ * BOUT_;
    size_t off0 = 0;
    size_t off2 = off0 + per * 1;
    size_t off4 = off2 + per * 25;
    size_t off6 = off4 + per * 81;
    size_t off8 = off6 + per * 169;

    const int nblocks = NB8 + NB6 + NB4 + NB2 + NB0;   // 3168
    s2conv_one<<<nblocks, 256, 0, stream>>>(x0, x2, x4, x6, x8,
                                            w0, w2, w4, w6, w8,
                                            bias, out,
                                            off0, off2, off4, off6, off8);
}